// Round 3
// baseline (248.674 us; speedup 1.0000x reference)
//
#include <hip/hip_runtime.h>

// CARAFE: N=8, C=256, H=W=64, UP=2, K=3 -> out (8,256,128,128) fp32
// Stage 1 (encoder): scalar-weight (SGPR) matmuls, LDS only for y-exchange.
// Stage 2 (reassemble): per-pixel 9-tap x 4-subpixel weighted sum + pixelshuffle.

#define EPS_BN 1e-5f

typedef float f32x2 __attribute__((ext_vector_type(2)));

__global__ __launch_bounds__(256) void carafe_encoder(
    const float* __restrict__ x,
    const float* __restrict__ w0, const float* __restrict__ b0,
    const float* __restrict__ g0, const float* __restrict__ be0,
    const float* __restrict__ m0, const float* __restrict__ v0,
    const float* __restrict__ w1, const float* __restrict__ b1,
    const float* __restrict__ g1, const float* __restrict__ be1,
    const float* __restrict__ m1, const float* __restrict__ v1,
    float* __restrict__ wts)
{
    __shared__ float ys[64 * 64];   // [o][w], conflict-free both ways

    const int tid = threadIdx.x;
    const int n   = blockIdx.x >> 6;     // 0..7
    const int hh  = blockIdx.x & 63;     // row
    const int w   = tid & 63;            // pixel col (lane)
    // wave id 0..3, forced wave-uniform so weight reads become s_load
    const int og  = __builtin_amdgcn_readfirstlane(tid >> 6);

    // ---- layer0: y[o][w], o = og*16 + j. Weights from SGPRs, x direct from global. ----
    float acc[16];
#pragma unroll
    for (int j = 0; j < 16; ++j) acc[j] = 0.f;

    const float* xp  = x + ((n * 256) * 64 + hh) * 64 + w;  // stride 4096 per channel
    const float* w0p = w0 + og * 16 * 256;                   // row-major [16][256], uniform base

#pragma unroll 8
    for (int c = 0; c < 256; ++c) {
        const float xv = xp[c * 4096];
#pragma unroll
        for (int j = 0; j < 16; ++j)
            acc[j] = fmaf(xv, w0p[j * 256 + c], acc[j]);
    }

    // BN0 + ReLU -> ys
#pragma unroll
    for (int j = 0; j < 16; ++j) {
        const int o = og * 16 + j;
        const float sc = g0[o] * rsqrtf(v0[o] + EPS_BN);
        const float sh = (b0[o] - m0[o]) * sc + be0[o];
        ys[o * 64 + w] = fmaxf(fmaf(acc[j], sc, sh), 0.f);
    }
    __syncthreads();

    // ---- layer1: enc[p][w], p = kk*4 + u, u = og (uniform). Scalar w1 reads. ----
    float e9[9];
#pragma unroll
    for (int kk = 0; kk < 9; ++kk) e9[kk] = 0.f;
    const int u = og;
    const float* w1p = w1 + u * 64;       // w1[(kk*4+u)*64 + o] = w1p[kk*256 + o]
#pragma unroll 4
    for (int o = 0; o < 64; ++o) {
        const float yv = ys[o * 64 + w];
#pragma unroll
        for (int kk = 0; kk < 9; ++kk)
            e9[kk] = fmaf(yv, w1p[kk * 256 + o], e9[kk]);
    }

    // BN1 + ReLU, softmax over kk (all in-register)
    float mx = -1e30f;
#pragma unroll
    for (int kk = 0; kk < 9; ++kk) {
        const int p = kk * 4 + u;
        const float sc = g1[p] * rsqrtf(v1[p] + EPS_BN);
        const float sh = (b1[p] - m1[p]) * sc + be1[p];
        float e = fmaxf(fmaf(e9[kk], sc, sh), 0.f);
        e9[kk] = e;
        mx = fmaxf(mx, e);
    }
    float s = 0.f;
#pragma unroll
    for (int kk = 0; kk < 9; ++kk) {
        e9[kk] = __expf(e9[kk] - mx);
        s += e9[kk];
    }
    const float inv = 1.f / s;
#pragma unroll
    for (int kk = 0; kk < 9; ++kk)
        wts[((n * 36 + kk * 4 + u) * 64 + hh) * 64 + w] = e9[kk] * inv;
}

// Stage 2: thread <-> (n, cg, h, w); 8 channels per thread.
__global__ __launch_bounds__(256) void carafe_reassemble(
    const float* __restrict__ x,
    const float* __restrict__ wts,
    float* __restrict__ out)
{
    const int t  = blockIdx.x * 256 + threadIdx.x;
    const int w  = t & 63;
    const int h  = (t >> 6) & 63;
    const int cg = (t >> 12) & 31;   // 32 groups of 8 channels
    const int n  = t >> 17;

    // load 36 softmax weights (plane stride H*W=4096, coalesced across lanes)
    float wt[36];
    const float* wp = wts + (n * 36) * 4096 + h * 64 + w;
#pragma unroll
    for (int p = 0; p < 36; ++p) wt[p] = wp[p * 4096];

#pragma unroll
    for (int i = 0; i < 8; ++i) {
        const int c = cg * 8 + i;
        const float* xp = x + (n * 256 + c) * 4096;
        float a0 = 0.f, a1 = 0.f, a2 = 0.f, a3 = 0.f;  // u = 0..3
#pragma unroll
        for (int dh = -1; dh <= 1; ++dh) {
            const int hhp = h + dh;
            const bool hv = (hhp >= 0) & (hhp < 64);
#pragma unroll
            for (int dw = -1; dw <= 1; ++dw) {
                const int wwp = w + dw;
                const bool vv = hv & (wwp >= 0) & (wwp < 64);
                const float xv = vv ? xp[hhp * 64 + wwp] : 0.f;
                const int k = (dh + 1) * 3 + (dw + 1);
                a0 = fmaf(xv, wt[k * 4 + 0], a0);
                a1 = fmaf(xv, wt[k * 4 + 1], a1);
                a2 = fmaf(xv, wt[k * 4 + 2], a2);
                a3 = fmaf(xv, wt[k * 4 + 3], a3);
            }
        }
        float* op = out + ((n * 256 + c) * 128 + 2 * h) * 128 + 2 * w;
        f32x2 r0; r0.x = a0; r0.y = a1;   // row 2h   : (u=0,u=1)
        f32x2 r1; r1.x = a2; r1.y = a3;   // row 2h+1 : (u=2,u=3)
        __builtin_nontemporal_store(r0, reinterpret_cast<f32x2*>(op));
        __builtin_nontemporal_store(r1, reinterpret_cast<f32x2*>(op + 128));
    }
}

extern "C" void kernel_launch(void* const* d_in, const int* in_sizes, int n_in,
                              void* d_out, int out_size, void* d_ws, size_t ws_size,
                              hipStream_t stream)
{
    const float* x   = (const float*)d_in[0];
    const float* w0  = (const float*)d_in[1];
    const float* b0  = (const float*)d_in[2];
    const float* g0  = (const float*)d_in[3];
    const float* be0 = (const float*)d_in[4];
    const float* m0  = (const float*)d_in[5];
    const float* v0  = (const float*)d_in[6];
    const float* w1  = (const float*)d_in[7];
    const float* b1  = (const float*)d_in[8];
    const float* g1  = (const float*)d_in[9];
    const float* be1 = (const float*)d_in[10];
    const float* m1  = (const float*)d_in[11];
    const float* v1  = (const float*)d_in[12];

    float* wts = (float*)d_ws;          // N*36*H*W floats = 4,718,592 B
    float* out = (float*)d_out;

    hipLaunchKernelGGL(carafe_encoder, dim3(512), dim3(256), 0, stream,
                       x, w0, b0, g0, be0, m0, v0, w1, b1, g1, be1, m1, v1, wts);
    // N*H*W*(C/8) threads = 1,048,576 -> 4096 blocks
    hipLaunchKernelGGL(carafe_reassemble, dim3(4096), dim3(256), 0, stream,
                       x, wts, out);
}

// Round 4
// 238.586 us; speedup vs baseline: 1.0423x; 1.0423x over previous
//
#include <hip/hip_runtime.h>

// CARAFE: N=8, C=256, H=W=64, UP=2, K=3 -> out (8,256,128,128) fp32
// Stage 1 (encoder): x staged in LDS (shared by 4 waves), weights via wave-uniform
//                    SGPR loads -> VALU-bound inner loop (1 ds_read_b32 + 16 FMA/ch).
// Stage 2 (reassemble): per-pixel 9-tap x 4-subpixel weighted sum + pixelshuffle
//                    (round-1 proven config: 4 ch/thread, plain float2 stores).

#define EPS_BN 1e-5f

typedef float f32x4 __attribute__((ext_vector_type(4)));

__global__ __launch_bounds__(256) void carafe_encoder(
    const float* __restrict__ x,
    const float* __restrict__ w0, const float* __restrict__ b0,
    const float* __restrict__ g0, const float* __restrict__ be0,
    const float* __restrict__ m0, const float* __restrict__ v0,
    const float* __restrict__ w1, const float* __restrict__ b1,
    const float* __restrict__ g1, const float* __restrict__ be1,
    const float* __restrict__ m1, const float* __restrict__ v1,
    float* __restrict__ wts)
{
    __shared__ float xs[256 * 64];  // [c][w] 64 KB
    __shared__ float ys[64 * 64];   // [o][w] 16 KB -> 80 KB total, 2 blocks/CU

    const int tid = threadIdx.x;
    const int n   = blockIdx.x >> 6;     // 0..7
    const int hh  = blockIdx.x & 63;     // row
    const int w   = tid & 63;            // pixel col (lane)
    // wave id 0..3, forced wave-uniform so weight reads become s_load
    const int og  = __builtin_amdgcn_readfirstlane(tid >> 6);

    // ---- stage x[n, :, hh, :] -> xs (vectorized, coalesced) ----
    {
        const f32x4* xg = reinterpret_cast<const f32x4*>(x + (n * 256) * 4096 + hh * 64);
        f32x4* xl = reinterpret_cast<f32x4*>(xs);
        // channel c contributes 16 float4s at global index c*1024 + 0..15
#pragma unroll
        for (int k = 0; k < 16; ++k) {
            const int i  = tid + k * 256;      // 0..4095
            const int cc = i >> 4;             // channel
            const int c4 = i & 15;             // float4 within row
            xl[cc * 16 + c4] = xg[cc * 1024 + c4];
        }
    }
    __syncthreads();

    // ---- layer0: y[o][w], o = og*16 + j. Weights from SGPRs, x from LDS. ----
    float acc[16];
#pragma unroll
    for (int j = 0; j < 16; ++j) acc[j] = 0.f;

    const float* w0p = w0 + og * 16 * 256;   // row-major [16][256], uniform base

#pragma unroll 8
    for (int c = 0; c < 256; ++c) {
        const float xv = xs[c * 64 + w];
#pragma unroll
        for (int j = 0; j < 16; ++j)
            acc[j] = fmaf(xv, w0p[j * 256 + c], acc[j]);
    }

    // BN0 + ReLU -> ys
#pragma unroll
    for (int j = 0; j < 16; ++j) {
        const int o = og * 16 + j;
        const float sc = g0[o] * rsqrtf(v0[o] + EPS_BN);
        const float sh = (b0[o] - m0[o]) * sc + be0[o];
        ys[o * 64 + w] = fmaxf(fmaf(acc[j], sc, sh), 0.f);
    }
    __syncthreads();

    // ---- layer1: enc[p][w], p = kk*4 + u, u = og (uniform). Scalar w1 reads. ----
    float e9[9];
#pragma unroll
    for (int kk = 0; kk < 9; ++kk) e9[kk] = 0.f;
    const int u = og;
    const float* w1p = w1 + u * 64;          // w1[(kk*4+u)*64 + o] = w1p[kk*256 + o]
#pragma unroll 4
    for (int o = 0; o < 64; ++o) {
        const float yv = ys[o * 64 + w];
#pragma unroll
        for (int kk = 0; kk < 9; ++kk)
            e9[kk] = fmaf(yv, w1p[kk * 256 + o], e9[kk]);
    }

    // BN1 + ReLU, softmax over kk (all in-register)
    float mx = -1e30f;
#pragma unroll
    for (int kk = 0; kk < 9; ++kk) {
        const int p = kk * 4 + u;
        const float sc = g1[p] * rsqrtf(v1[p] + EPS_BN);
        const float sh = (b1[p] - m1[p]) * sc + be1[p];
        float e = fmaxf(fmaf(e9[kk], sc, sh), 0.f);
        e9[kk] = e;
        mx = fmaxf(mx, e);
    }
    float s = 0.f;
#pragma unroll
    for (int kk = 0; kk < 9; ++kk) {
        e9[kk] = __expf(e9[kk] - mx);
        s += e9[kk];
    }
    const float inv = 1.f / s;
#pragma unroll
    for (int kk = 0; kk < 9; ++kk)
        wts[((n * 36 + kk * 4 + u) * 64 + hh) * 64 + w] = e9[kk] * inv;
}

// Stage 2: thread <-> (n, cg, h, w); 4 channels per thread (round-1 proven).
__global__ __launch_bounds__(256) void carafe_reassemble(
    const float* __restrict__ x,
    const float* __restrict__ wts,
    float* __restrict__ out)
{
    const int t  = blockIdx.x * 256 + threadIdx.x;
    const int w  = t & 63;
    const int h  = (t >> 6) & 63;
    const int cg = (t >> 12) & 63;
    const int n  = t >> 18;

    // load 36 weights (each plane stride H*W=4096, coalesced across lanes)
    float wt[36];
    const float* wp = wts + (n * 36) * 4096 + h * 64 + w;
#pragma unroll
    for (int p = 0; p < 36; ++p) wt[p] = wp[p * 4096];

#pragma unroll
    for (int i = 0; i < 4; ++i) {
        const int c = cg * 4 + i;
        const float* xp = x + (n * 256 + c) * 4096;
        float a0 = 0.f, a1 = 0.f, a2 = 0.f, a3 = 0.f;  // u = 0..3
#pragma unroll
        for (int dh = -1; dh <= 1; ++dh) {
            const int hhp = h + dh;
            const bool hv = (hhp >= 0) & (hhp < 64);
#pragma unroll
            for (int dw = -1; dw <= 1; ++dw) {
                const int wwp = w + dw;
                const bool vv = hv & (wwp >= 0) & (wwp < 64);
                const float xv = vv ? xp[hhp * 64 + wwp] : 0.f;
                const int k = (dh + 1) * 3 + (dw + 1);
                a0 = fmaf(xv, wt[k * 4 + 0], a0);
                a1 = fmaf(xv, wt[k * 4 + 1], a1);
                a2 = fmaf(xv, wt[k * 4 + 2], a2);
                a3 = fmaf(xv, wt[k * 4 + 3], a3);
            }
        }
        float* op = out + ((n * 256 + c) * 128 + 2 * h) * 128 + 2 * w;
        float2 r0; r0.x = a0; r0.y = a1;   // row 2h   : (u=0,u=1)
        float2 r1; r1.x = a2; r1.y = a3;   // row 2h+1 : (u=2,u=3)
        *reinterpret_cast<float2*>(op)       = r0;
        *reinterpret_cast<float2*>(op + 128) = r1;
    }
}

extern "C" void kernel_launch(void* const* d_in, const int* in_sizes, int n_in,
                              void* d_out, int out_size, void* d_ws, size_t ws_size,
                              hipStream_t stream)
{
    const float* x   = (const float*)d_in[0];
    const float* w0  = (const float*)d_in[1];
    const float* b0  = (const float*)d_in[2];
    const float* g0  = (const float*)d_in[3];
    const float* be0 = (const float*)d_in[4];
    const float* m0  = (const float*)d_in[5];
    const float* v0  = (const float*)d_in[6];
    const float* w1  = (const float*)d_in[7];
    const float* b1  = (const float*)d_in[8];
    const float* g1  = (const float*)d_in[9];
    const float* be1 = (const float*)d_in[10];
    const float* m1  = (const float*)d_in[11];
    const float* v1  = (const float*)d_in[12];

    float* wts = (float*)d_ws;          // N*36*H*W floats = 4,718,592 B
    float* out = (float*)d_out;

    hipLaunchKernelGGL(carafe_encoder, dim3(512), dim3(256), 0, stream,
                       x, w0, b0, g0, be0, m0, v0, w1, b1, g1, be1, m1, v1, wts);
    // N*H*W*(C/4) threads = 2,097,152 -> 8192 blocks
    hipLaunchKernelGGL(carafe_reassemble, dim3(8192), dim3(256), 0, stream,
                       x, wts, out);
}